// Round 1
// baseline (19219.646 us; speedup 1.0000x reference)
//
#include <hip/hip_runtime.h>

#define BB 64
#define NN 1000
#define FF 12
#define EE 64
#define HH 128
#define OO 16
#define GG 512

__device__ __forceinline__ float rcp_(float x){ return __builtin_amdgcn_rcpf(x); }
__device__ __forceinline__ float sigm_(float x){ return rcp_(1.0f + __expf(-x)); }
// exact algebraic form of tanh: (e^{2x}-1)/(e^{2x}+1) = 1 - 2/(e^{2x}+1)
__device__ __forceinline__ float tanh_(float x){ return 1.0f - 2.0f*rcp_(__expf(2.0f*x) + 1.0f); }

// rotate within 16-lane DPP row by 1 (direction resolved at runtime by probe)
__device__ __forceinline__ float ror1_(float x){
    int i = __float_as_int(x);
    i = __builtin_amdgcn_update_dpp(i, i, 0x121 /*row_ror:1*/, 0xF, 0xF, false);
    return __int_as_float(i);
}

__global__ __launch_bounds__(512, 2)
void decoder_kernel(const float* __restrict__ enc,   // (B,1,N,E)
                    const float* __restrict__ mean,  // (B,FUT,N,O)
                    const float* __restrict__ sv,    // (1,O)
                    const float* __restrict__ h0,    // (2,O)
                    const float* __restrict__ c0,    // (2,H)
                    const float* __restrict__ Wih0,  // (G, E+O)
                    const float* __restrict__ Whh0,  // (G, O)
                    const float* __restrict__ bih0,  // (G)
                    const float* __restrict__ bhh0,  // (G)
                    const float* __restrict__ Whr0,  // (O, H)
                    const float* __restrict__ Wih1,  // (G, O)
                    const float* __restrict__ Whh1,  // (G, O)
                    const float* __restrict__ bih1,  // (G)
                    const float* __restrict__ bhh1,  // (G)
                    const float* __restrict__ Whr1,  // (O, H)
                    float* __restrict__ out)         // (B,FUT,N,O)
{
    const int tid = threadIdx.x;
    const int b   = blockIdx.x;
    const int j16 = tid & 15;          // position within 16-lane DPP row
    const int tau = (tid >> 4) & 3;    // gate type row: 0=i 1=f 2=g 3=o
    const int wid = tid >> 6;          // wave id: owns cell slice [16*wid, 16*wid+16)
    const int g   = tau*128 + wid*16 + j16;   // this lane's gate index (both layers)

    // projection partials: [j][wave]; inner dim 12 for bank spread, use [0..8)
    __shared__ __align__(16) float s_pp1[2][16][12];   // h1 partials (ping-pong)
    __shared__ __align__(16) float s_pp2[16][12];      // h2 partials
    __shared__ __align__(16) float s_enc[2][64];       // enc(node) ping-pong

    // ---- DPP rotation direction probe (removes ROR direction ambiguity) ----
    int rr = __builtin_amdgcn_update_dpp(0, j16, 0x121, 0xF, 0xF, false);
    const int dstep = (rr == ((j16 + 1) & 15)) ? 1 : 15;

    // ---- rotated weights in registers: w[q] pairs with data after q rotations ----
    float wL[16], wH[16], wI[16], wH2[16], wP0[16], wP1[16];
    #pragma unroll
    for (int q = 0; q < 16; ++q){
        const int jj = (j16 + dstep*q) & 15;
        wL[q]  = Wih0[g*(EE+OO) + EE + jj];      // 'loop' (last+nm) input weights
        wH[q]  = Whh0[g*OO + jj];
        wI[q]  = Wih1[g*OO + jj];
        wH2[q] = Whh1[g*OO + jj];
        wP0[q] = Whr0[j16*HH + wid*16 + jj];     // projection: out j16, k-slice of wave
        wP1[q] = Whr1[j16*HH + wid*16 + jj];
    }
    const float bias0 = bih0[g] + bhh0[g];
    const float bias1 = bih1[g] + bhh1[g];

    const float* encB  = enc  + (size_t)b * NN * EE;
    const float* meanB = mean + (size_t)b * FF * NN * OO;
    float*       outB  = out  + (size_t)b * FF * NN * OO;

    // cell state for k = 16*wid + j16 (valid in rows tau=0,1; only tau=1 is consumed)
    float c1 = c0[wid*16 + j16];
    float c2 = c0[HH + wid*16 + j16];
    const float svj = sv[j16];

    // ---- prologue: node 0 enc + node_mean, seed projection partials ----
    if (tid < EE) s_enc[0][tid] = encB[tid];
    float nmj;
    {
        float a = 0.f;
        #pragma unroll
        for (int ff = 0; ff < FF; ++ff) a += meanB[(ff*NN)*OO + j16];
        nmj = a * (1.0f/12.0f);
    }
    if (tid < 128){
        int j = tid >> 3, w8 = tid & 7;
        s_pp1[0][j][w8] = (w8 == 0) ? h0[j]      : 0.f;
        s_pp2[j][w8]    = (w8 == 0) ? h0[OO + j] : 0.f;
    }
    __syncthreads();

    float pre0 = 0.f;
    float nm_next = 0.f;
    float encv = 0.f;
    float mld[12];

    int step = 0;
    #pragma unroll 1
    for (int n = 0; n < NN; ++n){
        #pragma unroll 1
        for (int f = 0; f < FF; ++f, ++step){
            const int rp = step & 1;
            const int wq = rp ^ 1;

            // ================= PHASE A (layer 0) =================
            // reduce projection partials -> h1_{t-1}, h2_{t-1} (all lanes, per j16)
            float4 pa = *(const float4*)&s_pp1[rp][j16][0];
            float4 pb = *(const float4*)&s_pp1[rp][j16][4];
            float4 qa = *(const float4*)&s_pp2[j16][0];
            float4 qb = *(const float4*)&s_pp2[j16][4];
            float h1j = (pa.x+pa.y)+(pa.z+pa.w)+((pb.x+pb.y)+(pb.z+pb.w));
            float h2j = (qa.x+qa.y)+(qa.z+qa.w)+((qb.x+qb.y)+(qb.z+qb.w));

            // deferred output write for step t-1 (uses OLD nmj; before nm update)
            if (step > 0 && tid < OO){
                const int fp = (f == 0) ? (FF-1) : (f-1);
                const int np = (f == 0) ? (n-1)  : n;
                outB[((size_t)fp*NN + np)*OO + j16] = h2j + nmj;
            }
            if (f == 0){
                if (n > 0) nmj = nm_next;          // switch to this node's mean
                // recompute per-node gate-0 constant: bias + enc-dot + nm-dot
                float pre = bias0;
                const float4* ep = (const float4*)&s_enc[n & 1][0];
                const float4* wp = (const float4*)(Wih0 + (size_t)g*(EE+OO));
                #pragma unroll
                for (int e4 = 0; e4 < 16; ++e4){
                    float4 ev = ep[e4]; float4 wv = wp[e4];
                    pre += ev.x*wv.x + ev.y*wv.y + ev.z*wv.z + ev.w*wv.w;
                }
                float nv = nmj;
                #pragma unroll
                for (int q = 0; q < 16; ++q){ pre += nv * wL[q]; nv = ror1_(nv); }
                pre0 = pre;
            }

            const float lastj = (step == 0) ? svj : h2j;

            // gates0: rotate-and-FMA over last(+nm folded) and h1, K=16+16
            float aL = pre0, aH = 0.f, lv = lastj, hv = h1j;
            #pragma unroll
            for (int q = 0; q < 16; ++q){
                aL += lv * wL[q];
                aH += hv * wH[q];
                lv = ror1_(lv); hv = ror1_(hv);
            }
            float gv0 = aL + aH;
            float act = (tau == 2) ? tanh_(gv0) : sigm_(gv0);

            // cell0: c' = sigm(f)*c + sigm(i)*tanh(g); hfull = sigm(o)*tanh(c')
            float fc = act * c1;                  // valid in row tau=1
            float r1 = __shfl_xor(act, 32);       // tau0<->tau2, tau1<->tau3
            float P  = act * r1;                  // rows 0,2: sigm(i)*tanh(g)
            float s2 = (tau & 1) ? fc : P;
            float r2 = __shfl_xor(s2, 16);        // tau0<->tau1, tau2<->tau3
            float cn = s2 + r2;                   // rows 0,1: new c1
            c1 = cn;
            float hfull = r1 * tanh_(cn);         // row 1: sigm(o)*tanh(c1')

            // proj0 partial for this wave's k-slice (valid in row tau=1)
            float pp = 0.f, pv = hfull;
            #pragma unroll
            for (int q = 0; q < 16; ++q){ pp += pv * wP0[q]; pv = ror1_(pv); }
            if (tau == 1) s_pp1[wq][j16][wid] = pp;
            __syncthreads();

            // ================= PHASE B (layer 1) =================
            float4 ra = *(const float4*)&s_pp1[wq][j16][0];
            float4 rb = *(const float4*)&s_pp1[wq][j16][4];
            float h1n = (ra.x+ra.y)+(ra.z+ra.w)+((rb.x+rb.y)+(rb.z+rb.w));

            // prefetch node n+1 (issue early, consume 2 steps later)
            if (f == 0 && n + 1 < NN){
                if (tid < EE) encv = encB[(size_t)(n+1)*EE + tid];
                #pragma unroll
                for (int ff = 0; ff < FF; ++ff)
                    mld[ff] = meanB[((size_t)ff*NN + (n+1))*OO + j16];
            }
            if (f == 2 && n + 1 < NN){
                if (tid < EE) s_enc[(n+1) & 1][tid] = encv;
                float a = 0.f;
                #pragma unroll
                for (int ff = 0; ff < FF; ++ff) a += mld[ff];
                nm_next = a * (1.0f/12.0f);
            }

            // gates1: inputs h1_t (new) and h2_{t-1} (register), K=16+16
            float aI = bias1, aH2 = 0.f, xv = h1n, yv = h2j;
            #pragma unroll
            for (int q = 0; q < 16; ++q){
                aI  += xv * wI[q];
                aH2 += yv * wH2[q];
                xv = ror1_(xv); yv = ror1_(yv);
            }
            float gv1 = aI + aH2;
            float act1 = (tau == 2) ? tanh_(gv1) : sigm_(gv1);

            float fc1 = act1 * c2;
            float r1b = __shfl_xor(act1, 32);
            float Pb  = act1 * r1b;
            float s2b = (tau & 1) ? fc1 : Pb;
            float r2b = __shfl_xor(s2b, 16);
            float cnb = s2b + r2b;
            c2 = cnb;
            float hfull2 = r1b * tanh_(cnb);

            float qq = 0.f, qv = hfull2;
            #pragma unroll
            for (int q = 0; q < 16; ++q){ qq += qv * wP1[q]; qv = ror1_(qv); }
            if (tau == 1) s_pp2[j16][wid] = qq;
            __syncthreads();
        }
    }

    // epilogue: output for the final step (n=NN-1, f=FF-1)
    {
        float4 qa = *(const float4*)&s_pp2[j16][0];
        float4 qb = *(const float4*)&s_pp2[j16][4];
        float h2f = (qa.x+qa.y)+(qa.z+qa.w)+((qb.x+qb.y)+(qb.z+qb.w));
        if (tid < OO)
            outB[((size_t)(FF-1)*NN + (NN-1))*OO + j16] = h2f + nmj;
    }
}

extern "C" void kernel_launch(void* const* d_in, const int* in_sizes, int n_in,
                              void* d_out, int out_size, void* d_ws, size_t ws_size,
                              hipStream_t stream) {
    const float* enc  = (const float*)d_in[0];
    const float* mean = (const float*)d_in[1];
    const float* sv   = (const float*)d_in[2];
    const float* h0   = (const float*)d_in[3];
    const float* c0   = (const float*)d_in[4];
    const float* Wih0 = (const float*)d_in[5];
    const float* Whh0 = (const float*)d_in[6];
    const float* bih0 = (const float*)d_in[7];
    const float* bhh0 = (const float*)d_in[8];
    const float* Whr0 = (const float*)d_in[9];
    const float* Wih1 = (const float*)d_in[10];
    const float* Whh1 = (const float*)d_in[11];
    const float* bih1 = (const float*)d_in[12];
    const float* bhh1 = (const float*)d_in[13];
    const float* Whr1 = (const float*)d_in[14];
    float* out = (float*)d_out;

    decoder_kernel<<<dim3(BB), dim3(512), 0, stream>>>(
        enc, mean, sv, h0, c0,
        Wih0, Whh0, bih0, bhh0, Whr0,
        Wih1, Whh1, bih1, bhh1, Whr1,
        out);
}